// Round 3
// baseline (172.014 us; speedup 1.0000x reference)
//
#include <hip/hip_runtime.h>

// Problem constants
#define B_    256
#define C_    256
#define CH_   128
#define N_    196           // H*W = 14*14
#define NF4   49            // 196 floats = 49 float4 per (b,c) row
#define NROW4 12544         // C_ * NF4 float4 per batch slab
#define EPS   1e-5f

typedef float f32x4 __attribute__((ext_vector_type(4)));   // native vec for NT store

// ---------------------------------------------------------------------------
// K1: per-batch reduction + channel mix. Grid 256 (one block per b), 1024 thr.
//
// Math (softmax over singleton axis == ones, so Z is constant over n):
//   ysum[c] = sum_n y[b,c,n]
//   t[k]    = sum_c Wv[k,c] * ysum[c]          (reassociated: no WzvT product)
//   z[o]    = alpha[o] * sum_k Wz[o,k] * t[k] + (bn_b[o] - bn_m[o]*alpha[o])
//   alpha[o]= bn_w[o] * rsqrt(bn_var[o]+eps)
//
// Phase A: wave w reduces rows [16w, 16w+16) of y[b] (wave-wide float4 loads,
//          shuffle butterfly). Phase B1/B2: wave-per-row dots on Wv / Wz with
//          coalesced float4/float2 row loads (weights are L2-resident, 256 KB
//          shared by all 256 blocks). Only 1 KB written to global per block.
// ---------------------------------------------------------------------------
__global__ __launch_bounds__(1024) void k_zs(const float* __restrict__ y,
                                             const float* __restrict__ Wv,
                                             const float* __restrict__ Wz,
                                             const float* __restrict__ bnw,
                                             const float* __restrict__ bnb,
                                             const float* __restrict__ bnm,
                                             const float* __restrict__ bnv,
                                             float* __restrict__ Zs) {
    __shared__ float sY[C_];
    __shared__ float sT[CH_];

    int b    = blockIdx.x;
    int tid  = threadIdx.x;
    int w    = tid >> 6;       // wave id 0..15
    int lane = tid & 63;

    // ---- Phase A: row sums of y[b] into sY -------------------------------
    const float4* yb = (const float4*)y + (size_t)b * NROW4;
    #pragma unroll
    for (int i = 0; i < 16; i += 4) {
        float s[4];
        #pragma unroll
        for (int j = 0; j < 4; j++) {
            int r = (w << 4) + i + j;
            float4 v = make_float4(0.f, 0.f, 0.f, 0.f);
            if (lane < NF4) v = yb[r * NF4 + lane];
            s[j] = (v.x + v.y) + (v.z + v.w);
        }
        #pragma unroll
        for (int off = 32; off > 0; off >>= 1) {
            #pragma unroll
            for (int j = 0; j < 4; j++) s[j] += __shfl_down(s[j], off, 64);
        }
        if (lane == 0) {
            #pragma unroll
            for (int j = 0; j < 4; j++) sY[(w << 4) + i + j] = s[j];
        }
    }
    __syncthreads();

    // ---- Phase B1: t[k] = Wv[k,:] . sY   (wave w handles k = 8w..8w+7) ---
    #pragma unroll
    for (int j = 0; j < 8; j++) {
        int k = (w << 3) + j;
        float4 wv = ((const float4*)(Wv + k * C_))[lane];   // c = 4*lane..+3
        float s = wv.x * sY[4 * lane + 0] + wv.y * sY[4 * lane + 1]
                + wv.z * sY[4 * lane + 2] + wv.w * sY[4 * lane + 3];
        #pragma unroll
        for (int off = 32; off > 0; off >>= 1) s += __shfl_down(s, off, 64);
        if (lane == 0) sT[k] = s;
    }
    __syncthreads();

    // ---- Phase B2: z[o] = alpha*Wz[o,:].t + beta (wave w: o = 16w..16w+15)
    #pragma unroll
    for (int j = 0; j < 16; j++) {
        int o = (w << 4) + j;
        float2 wz = ((const float2*)(Wz + o * CH_))[lane];  // k = 2*lane..+1
        float s = wz.x * sT[2 * lane + 0] + wz.y * sT[2 * lane + 1];
        #pragma unroll
        for (int off = 32; off > 0; off >>= 1) s += __shfl_down(s, off, 64);
        if (lane == 0) {
            float alpha = bnw[o] * rsqrtf(bnv[o] + EPS);
            Zs[b * C_ + o] = s * alpha + bnb[o] - bnm[o] * alpha;
        }
    }
}

// ---------------------------------------------------------------------------
// K2: out[b,c,n] = x[b,c,n] + Zs[b,c]. One float4 per thread, fully
// coalesced; Zs reads are 49-thread broadcasts served from L1/L2.
// Grid 12544 x 256 => high occupancy (VGPR-light, no LDS), streams at HBM BW.
// Nontemporal stores keep the write-once output from thrashing L2/L3.
// ---------------------------------------------------------------------------
__global__ __launch_bounds__(256) void k_out(const float* __restrict__ x,
                                             const float* __restrict__ Zs,
                                             float* __restrict__ out) {
    int idx = blockIdx.x * blockDim.x + threadIdx.x;  // float4 index
    int row = idx / NF4;                              // magic-multiply
    float z = Zs[row];
    f32x4 v = ((const f32x4*)x)[idx];
    v.x += z; v.y += z; v.z += z; v.w += z;
    __builtin_nontemporal_store(v, (f32x4*)out + idx);
}

extern "C" void kernel_launch(void* const* d_in, const int* in_sizes, int n_in,
                              void* d_out, int out_size, void* d_ws, size_t ws_size,
                              hipStream_t stream) {
    const float* x   = (const float*)d_in[0];
    const float* y   = (const float*)d_in[1];
    // d_in[2] = Wq, d_in[3] = Wk : dead (softmax over singleton axis == ones)
    const float* Wv  = (const float*)d_in[4];
    const float* Wz  = (const float*)d_in[5];
    const float* bnw = (const float*)d_in[6];
    const float* bnb = (const float*)d_in[7];
    const float* bnm = (const float*)d_in[8];
    const float* bnv = (const float*)d_in[9];
    float* out = (float*)d_out;

    float* Zs = (float*)d_ws;   // 256*256 floats

    k_zs<<<B_, 1024, 0, stream>>>(y, Wv, Wz, bnw, bnb, bnm, bnv, Zs);
    k_out<<<(B_ * C_ * NF4) / 256, 256, 0, stream>>>(x, Zs, out);
}